// Round 2
// 1820.954 us; speedup vs baseline: 1.2589x; 1.2589x over previous
//
#include <hip/hip_runtime.h>

#define T_STEPS 4096
#define BATCH   64
#define INDIM   4
#define H       256
#define OUTD    2
#define CHUNK   32
#define SLOT_DW 36                    // dwords per k-quarter: 32 + 4 skew
#define ENT_DW  (4*SLOT_DW)           // 144 dwords per stored h vector
#define ENT_B   (4*ENT_DW)            // 576 bytes
#define RING_DW (CHUNK*ENT_DW)        // 4608 dwords (18 KB)
#define WF_DW   (OUTD*(H/2))          // 256 dwords packed Wf
#define XS_DW   (CHUNK*INDIM)         // 128 dwords: staged x for the chunk

typedef __fp16 half2v __attribute__((ext_vector_type(2)));

__device__ __forceinline__ float fast_tanh(float x) {
    float ax = fabsf(x);
    float e  = __expf(-2.0f * ax);
    float r  = (1.0f - e) * __builtin_amdgcn_rcpf(1.0f + e);
    return copysignf(r, x);
}

// quad_perm butterfly add: CTRL=0xB1 is lane^1, CTRL=0x4E is lane^2
template<int CTRL>
__device__ __forceinline__ float qadd(float a) {
    int s = __builtin_amdgcn_update_dpp(0, __builtin_bit_cast(int, a),
                                        CTRL, 0xf, 0xf, true);
    return a + __builtin_bit_cast(float, s);
}
#define QX1 0xB1
#define QX2 0x4E

// 4-wave variant of the R8/R9 structure. Rationale: the 8-wave kernel is
// DS-pipe bound — 8 waves x 9 ds_read_b128/step ~ 864 cy/step of LDS
// occupancy (all waves re-read identical h slices). Per-lane read volume
// is fixed (its 64-value k-slice), so DS instructions/step = 9 x #waves:
// 4 waves halves the DS time. Each 4-lane quad owns 4 rows (rows 4q..4q+3),
// each lane 4 rows x its 64-k slice (128 fdot2, weights 128 VGPR resident),
// quad-butterfly reduce with early select, every lane finalizes row t.
__global__ __attribute__((amdgpu_waves_per_eu(1, 1))) __launch_bounds__(256)
void elman_kernel(const float* __restrict__ input,
                  const float* __restrict__ Wi,
                  const float* __restrict__ bi,
                  const float* __restrict__ Wh,
                  const float* __restrict__ bh,
                  const float* __restrict__ Wf,
                  const float* __restrict__ bf,
                  float* __restrict__ out)
{
    const int b  = blockIdx.x;
    const int t  = threadIdx.x;
    const int q  = t >> 2;        // quad id 0..63 -> rows 4q..4q+3
    const int ko = t & 3;         // k-quarter
    const int k0 = ko * 64;

    __shared__ unsigned int lds[RING_DW + WF_DW + XS_DW];
    unsigned int* ring   = lds;
    unsigned int* wf_pk  = lds + RING_DW;
    float*        xstage = (float*)(lds + RING_DW + WF_DW);

    // --- weights: 4 rows x 64 k packed f16 -> 128 dwords (resident) ---
    half2v w[4][32];
    #pragma unroll
    for (int r = 0; r < 4; ++r) {
        const float* p = Wh + (size_t)(4 * q + r) * H + k0;
        #pragma unroll
        for (int j = 0; j < 16; ++j) {
            float4 a = *(const float4*)(p + 4 * j);
            w[r][2 * j]     = __builtin_amdgcn_cvt_pkrtz(a.x, a.y);
            w[r][2 * j + 1] = __builtin_amdgcn_cvt_pkrtz(a.z, a.w);
        }
    }
    #pragma unroll
    for (int r = 0; r < 4; ++r)
        #pragma unroll
        for (int j = 0; j < 32; ++j) {
            float f = __builtin_bit_cast(float, w[r][j]);
            asm volatile("" : "+v"(f));
            w[r][j] = __builtin_bit_cast(half2v, f);
        }

    // each lane finalizes row t  (row = 4q + ko = t)
    const float4 wim   = *(const float4*)(Wi + t * INDIM);
    const float  biasm = bi[t] + bh[t];
    const float  bf0   = bf[0], bf1 = bf[1];
    const int    boff  = (t >> 6) * (SLOT_DW * 4) + (t & 63) * 2;  // bytes

    {   // pack Wf: all 256 lanes
        const int o = t >> 7, e = t & 127;
        wf_pk[t] = __builtin_bit_cast(unsigned int,
            __builtin_amdgcn_cvt_pkrtz(Wf[o * H + 2 * e], Wf[o * H + 2 * e + 1]));
    }
    if (t < H / 2) ring[(CHUNK - 1) * ENT_DW + (t >> 5) * SLOT_DW + (t & 31)] = 0u;
    __syncthreads();

    const unsigned int rd_off = (unsigned int)(ko * SLOT_DW);

    for (int chunk = 0; chunk < T_STEPS / CHUNK; ++chunk) {
        // ---- stage this chunk's x into LDS (only VMEM reads per chunk) ----
        if (t < CHUNK) {
            const int s = chunk * CHUNK + t;
            ((float4*)xstage)[t] = *(const float4*)(input + ((size_t)s * BATCH + b) * INDIM);
        }
        __syncthreads();   // drains the staging loads ONCE per chunk

        #pragma unroll 1
        for (int i = 0; i < CHUNK; ++i) {
            const unsigned int* hb =
                ring + ((i + CHUNK - 1) & (CHUNK - 1)) * ENT_DW + rd_off;
            uint4 hv[8];
            #pragma unroll
            for (int j = 0; j < 8; ++j) hv[j] = *(const uint4*)(hb + 4 * j);
            const float4 xs = *((const float4*)xstage + i);

            float acc0 = 0.f, acc1 = 0.f, acc2 = 0.f, acc3 = 0.f;
            #pragma unroll
            for (int j = 0; j < 8; ++j) {
                half2v h0 = __builtin_bit_cast(half2v, hv[j].x);
                half2v h1 = __builtin_bit_cast(half2v, hv[j].y);
                half2v h2 = __builtin_bit_cast(half2v, hv[j].z);
                half2v h3 = __builtin_bit_cast(half2v, hv[j].w);
                acc0 = __builtin_amdgcn_fdot2(w[0][4 * j],     h0, acc0, false);
                acc1 = __builtin_amdgcn_fdot2(w[1][4 * j],     h0, acc1, false);
                acc2 = __builtin_amdgcn_fdot2(w[2][4 * j],     h0, acc2, false);
                acc3 = __builtin_amdgcn_fdot2(w[3][4 * j],     h0, acc3, false);
                acc0 = __builtin_amdgcn_fdot2(w[0][4 * j + 1], h1, acc0, false);
                acc1 = __builtin_amdgcn_fdot2(w[1][4 * j + 1], h1, acc1, false);
                acc2 = __builtin_amdgcn_fdot2(w[2][4 * j + 1], h1, acc2, false);
                acc3 = __builtin_amdgcn_fdot2(w[3][4 * j + 1], h1, acc3, false);
                acc0 = __builtin_amdgcn_fdot2(w[0][4 * j + 2], h2, acc0, false);
                acc1 = __builtin_amdgcn_fdot2(w[1][4 * j + 2], h2, acc1, false);
                acc2 = __builtin_amdgcn_fdot2(w[2][4 * j + 2], h2, acc2, false);
                acc3 = __builtin_amdgcn_fdot2(w[3][4 * j + 2], h2, acc3, false);
                acc0 = __builtin_amdgcn_fdot2(w[0][4 * j + 3], h3, acc0, false);
                acc1 = __builtin_amdgcn_fdot2(w[1][4 * j + 3], h3, acc1, false);
                acc2 = __builtin_amdgcn_fdot2(w[2][4 * j + 3], h3, acc2, false);
                acc3 = __builtin_amdgcn_fdot2(w[3][4 * j + 3], h3, acc3, false);
            }

            // quad butterfly reduce with early select:
            // stage 1 (lane^1): pair partial sums; pick accs by row parity.
            // stage 2 (lane^2): cross-pair sums; pick by bit1.
            // Result: lane ko holds full sum of row 4q+ko == t.
            acc0 = qadd<QX1>(acc0);
            acc1 = qadd<QX1>(acc1);
            acc2 = qadd<QX1>(acc2);
            acc3 = qadd<QX1>(acc3);
            float A  = (ko & 1) ? acc1 : acc0;
            float Bv = (ko & 1) ? acc3 : acc2;
            A  = qadd<QX2>(A);
            Bv = qadd<QX2>(Bv);
            float accm = (ko & 2) ? Bv : A;

            float pre = accm + biasm +
                xs.x * wim.x + xs.y * wim.y + xs.z * wim.z + xs.w * wim.w;
            __fp16 h16 = (__fp16)fast_tanh(pre);
            *(__fp16*)((char*)ring + i * ENT_B + boff) = h16;

            __syncthreads();   // drains only the b16 write (no VMEM in loop)
        }

        // --- deferred output head: 64 tasks x 4 lanes ---
        {
            const int task = t >> 2;      // 0..63
            const int s    = task >> 1;   // step in chunk
            const int o    = task & 1;    // output channel
            const int sub  = t & 3;       // k-quarter
            const unsigned int* hp = ring + s * ENT_DW + sub * SLOT_DW;
            const unsigned int* wp = wf_pk + o * (H / 2) + sub * 32;

            float acc = 0.f;
            #pragma unroll
            for (int j = 0; j < 8; ++j) {
                uint4 hq = *(const uint4*)(hp + 4 * j);
                uint4 wq = *(const uint4*)(wp + 4 * j);
                acc = __builtin_amdgcn_fdot2(__builtin_bit_cast(half2v, wq.x),
                                             __builtin_bit_cast(half2v, hq.x), acc, false);
                acc = __builtin_amdgcn_fdot2(__builtin_bit_cast(half2v, wq.y),
                                             __builtin_bit_cast(half2v, hq.y), acc, false);
                acc = __builtin_amdgcn_fdot2(__builtin_bit_cast(half2v, wq.z),
                                             __builtin_bit_cast(half2v, hq.z), acc, false);
                acc = __builtin_amdgcn_fdot2(__builtin_bit_cast(half2v, wq.w),
                                             __builtin_bit_cast(half2v, hq.w), acc, false);
            }
            acc = qadd<QX1>(acc);
            acc = qadd<QX2>(acc);

            if (sub == 0) {
                out[((size_t)(chunk * CHUNK + s) * BATCH + b) * OUTD + o] =
                    fast_tanh(acc + (o ? bf1 : bf0));
            }
            __syncthreads();  // protect ring before next chunk overwrites
        }
    }
}

extern "C" void kernel_launch(void* const* d_in, const int* in_sizes, int n_in,
                              void* d_out, int out_size, void* d_ws, size_t ws_size,
                              hipStream_t stream) {
    const float* input = (const float*)d_in[0];
    // d_in[1] = target (unused by forward)
    const float* Wi = (const float*)d_in[2];
    const float* bi = (const float*)d_in[3];
    const float* bh = (const float*)d_in[5];
    const float* Wh = (const float*)d_in[4];
    const float* Wf = (const float*)d_in[6];
    const float* bf = (const float*)d_in[7];
    float* out = (float*)d_out;

    elman_kernel<<<dim3(BATCH), dim3(256), 0, stream>>>(
        input, Wi, bi, Wh, bh, Wf, bf, out);
}